// Round 7
// baseline (51.522 us; speedup 1.0000x reference)
//
#include <hip/hip_runtime.h>

// LinearCondensed: out[b,o] = sum_k w[o,k] * x[b, idx[o,k]] + bias[o]
// B=2048, IN_F=4096, OUT_F=4096, K=32, f32 in/out (idx int32).
//
// v6: BARRIER-FREE main loop. Block = 8 batch rows x 2048 outputs.
// Prologue stages the 8 rows into LDS as packed f16 (xs[c] = col c of 8 rows,
// one int4 -> one ds_read_b128 gathers 8 rows), ONE __syncthreads, then LDS
// is read-only: each thread loops over 4 output chunks, streaming idx/w
// (coalesced 16B loads, L2-resident after first touch per XCD) and gathering.
// No barriers, no LDS rewrite, no prefetch array -> latency hidden by TLP
// (2 blocks/CU x 8 independent waves). x read exactly once from HBM.

constexpr int IN_F  = 4096;
constexpr int OUT_F = 4096;
constexpr int K     = 32;
constexpr int BT    = 8;                       // batch rows per block
constexpr int THREADS = 512;
constexpr int O_PER_BLOCK = OUT_F / 2;         // 2048 (half per block)
constexpr int OCH = O_PER_BLOCK / THREADS;     // 4 o-chunks per thread
constexpr int CPT = IN_F / THREADS;            // 8 columns staged per thread

typedef __fp16 h2_t __attribute__((ext_vector_type(2)));

__device__ __forceinline__ int pack_f16(float lo, float hi) {
    union { h2_t h; int i; } cv;
    cv.h = __builtin_amdgcn_cvt_pkrtz(lo, hi);   // v_cvt_pkrtz_f16_f32
    return cv.i;
}
__device__ __forceinline__ float h_lo(int u) {
    union { int i; h2_t h; } cv; cv.i = u; return (float)cv.h[0];
}
__device__ __forceinline__ float h_hi(int u) {
    union { int i; h2_t h; } cv; cv.i = u; return (float)cv.h[1];
}

__global__ __launch_bounds__(THREADS)
void lc_kernel(const float* __restrict__ x,
               const float* __restrict__ w,
               const float* __restrict__ bias,
               const int* __restrict__ idx,
               float* __restrict__ out) {
    // xs[c] = {rows 0..7 of col c, 4x packed f16 pairs} -- 64 KiB, 2 blocks/CU
    __shared__ int4 xs[IN_F];
    const int tid  = threadIdx.x;
    const int pair = blockIdx.x >> 1;          // which 8-row group
    const int half = blockIdx.x & 1;           // which output half
    const int b0   = pair * BT;

    // ---- prologue: stage 8 rows as f16, one barrier, then LDS is read-only ----
    {
        const float* xr = x + (size_t)b0 * IN_F;
#pragma unroll
        for (int j = 0; j < CPT; ++j) {
            const int c = tid + j * THREADS;
            float v[BT];
#pragma unroll
            for (int r = 0; r < BT; ++r) v[r] = xr[(size_t)r * IN_F + c];
            int4 pk;
            pk.x = pack_f16(v[0], v[1]);
            pk.y = pack_f16(v[2], v[3]);
            pk.z = pack_f16(v[4], v[5]);
            pk.w = pack_f16(v[6], v[7]);
            xs[c] = pk;
        }
    }
    __syncthreads();

    const char* xb = reinterpret_cast<const char*>(&xs[0]);
    const int obase = half * O_PER_BLOCK + tid;

#pragma unroll 1
    for (int oc = 0; oc < OCH; ++oc) {
        const int o = obase + oc * THREADS;

        // stream this o's idx row + weight row (16 x 16B coalesced; idx+w are
        // 1MB total -> L2-resident per XCD after first touch)
        const int4*   ip = reinterpret_cast<const int4*>(idx + (size_t)o * K);
        const float4* wp = reinterpret_cast<const float4*>(w + (size_t)o * K);
        int4   iq[K / 4];
        float4 wq[K / 4];
#pragma unroll
        for (int kk = 0; kk < K / 4; ++kk) { iq[kk] = ip[kk]; wq[kk] = wp[kk]; }
        const float bv = bias[o];

        float acc[BT];
#pragma unroll
        for (int r = 0; r < BT; ++r) acc[r] = bv;

        // 32 ds_read_b128 gathers, each feeding 8 row-accumulators (fma_mix)
#pragma unroll
        for (int kk = 0; kk < K / 4; ++kk) {
            const int4 i4 = iq[kk];
            const float4 w4 = wq[kk];
            int4 v;
            v = *reinterpret_cast<const int4*>(xb + (i4.x << 4));
            acc[0] += w4.x * h_lo(v.x);  acc[1] += w4.x * h_hi(v.x);
            acc[2] += w4.x * h_lo(v.y);  acc[3] += w4.x * h_hi(v.y);
            acc[4] += w4.x * h_lo(v.z);  acc[5] += w4.x * h_hi(v.z);
            acc[6] += w4.x * h_lo(v.w);  acc[7] += w4.x * h_hi(v.w);
            v = *reinterpret_cast<const int4*>(xb + (i4.y << 4));
            acc[0] += w4.y * h_lo(v.x);  acc[1] += w4.y * h_hi(v.x);
            acc[2] += w4.y * h_lo(v.y);  acc[3] += w4.y * h_hi(v.y);
            acc[4] += w4.y * h_lo(v.z);  acc[5] += w4.y * h_hi(v.z);
            acc[6] += w4.y * h_lo(v.w);  acc[7] += w4.y * h_hi(v.w);
            v = *reinterpret_cast<const int4*>(xb + (i4.z << 4));
            acc[0] += w4.z * h_lo(v.x);  acc[1] += w4.z * h_hi(v.x);
            acc[2] += w4.z * h_lo(v.y);  acc[3] += w4.z * h_hi(v.y);
            acc[4] += w4.z * h_lo(v.z);  acc[5] += w4.z * h_hi(v.z);
            acc[6] += w4.z * h_lo(v.w);  acc[7] += w4.z * h_hi(v.w);
            v = *reinterpret_cast<const int4*>(xb + (i4.w << 4));
            acc[0] += w4.w * h_lo(v.x);  acc[1] += w4.w * h_hi(v.x);
            acc[2] += w4.w * h_lo(v.y);  acc[3] += w4.w * h_hi(v.y);
            acc[4] += w4.w * h_lo(v.z);  acc[5] += w4.w * h_hi(v.z);
            acc[6] += w4.w * h_lo(v.w);  acc[7] += w4.w * h_hi(v.w);
        }

        // coalesced stores: 8 rows x 256B per wave
        float* op = out + (size_t)b0 * OUT_F + o;
#pragma unroll
        for (int r = 0; r < BT; ++r) op[(size_t)r * OUT_F] = acc[r];
    }
}

extern "C" void kernel_launch(void* const* d_in, const int* in_sizes, int n_in,
                              void* d_out, int out_size, void* d_ws, size_t ws_size,
                              hipStream_t stream) {
    const float* x    = (const float*)d_in[0];
    const float* w    = (const float*)d_in[1];
    const float* bias = (const float*)d_in[2];
    const int*   idx  = (const int*)d_in[3];
    float* out = (float*)d_out;

    const int Bv = in_sizes[0] / IN_F;            // 2048
    const int nblocks = (Bv / BT) * 2;            // 512: 256 row-groups x 2 halves
    lc_kernel<<<dim3(nblocks), dim3(THREADS), 0, stream>>>(x, w, bias, idx, out);
}